// Round 3
// baseline (436.186 us; speedup 1.0000x reference)
//
#include <hip/hip_runtime.h>
#include <hip/hip_bf16.h>

// SparseDiffusionModel on MI355X — dtype-adaptive (fp32 or bf16 inputs).
// Identity: everything between `features` and attention is affine in features,
// and the query is one token/batch:
//   score[i,h] = f_i . u[b_i,h] + cq[b_i,h],  u = Wtok@Wk@Wik[:,hblk]@q_h / sqrt(32)
//   ctx[b,h]   = ((wbar@Wtok+btok)@Wv+bv)@Wiv[:,hblk]+biv,  wbar = sum_i attn*f_i
// => ONE streaming pass over features + tiny per-batch GEMMs.
//
// Rounds 1-2 failed with NaN: reading fp32 buffers as bf16 turns mantissa
// halves into NaN bit patterns that enter w via phase-2 products. Fix: device-
// side dtype detection (kDet) + templated loads everywhere.
//
// ws layout (floats): flag@0 | q@64[8192] | u[32768] | cq[256] | l[256] | w[32768]
// total ~297 KB.

typedef unsigned short ushort_t;
typedef unsigned int uint_t;

#define NB 64
#define CENC 128
#define HID 512
#define RSQRT32 0.17677669529663689f

__device__ __forceinline__ float blo(uint_t u){ return __uint_as_float(u << 16); }
__device__ __forceinline__ float bhi(uint_t u){ return __uint_as_float(u & 0xffff0000u); }
__device__ __forceinline__ ushort_t f2bf(float f){
    uint_t u = __float_as_uint(f);
    u += 0x7fffu + ((u >> 16) & 1u);
    return (ushort_t)(u >> 16);
}

template<bool BF16> struct Ld;
template<> struct Ld<true> {
    static __device__ __forceinline__ float at(const void* p, long i) {
        return __uint_as_float(((uint_t)((const ushort_t*)p)[i]) << 16);
    }
    static __device__ __forceinline__ void v8(const void* p, long i, float* o) {
        uint4 v = *(const uint4*)((const ushort_t*)p + i);
        o[0]=blo(v.x); o[1]=bhi(v.x); o[2]=blo(v.y); o[3]=bhi(v.y);
        o[4]=blo(v.z); o[5]=bhi(v.z); o[6]=blo(v.w); o[7]=bhi(v.w);
    }
};
template<> struct Ld<false> {
    static __device__ __forceinline__ float at(const void* p, long i) {
        return ((const float*)p)[i];
    }
    static __device__ __forceinline__ void v8(const void* p, long i, float* o) {
        const float4* q = (const float4*)((const float*)p + i);
        float4 a = q[0], b = q[1];
        o[0]=a.x; o[1]=a.y; o[2]=a.z; o[3]=a.w;
        o[4]=b.x; o[5]=b.y; o[6]=b.z; o[7]=b.w;
    }
};

// ---------------------------------------------------------------------------
// Detection: scan first 4096 ushorts of features.
//  - any bf16-exponent >=140  -> raw fp32 (random mantissa halves)
//  - >50% even-position ushorts == 0 -> fp32 holding bf16-rounded values
//  - else -> true bf16 buffer
__global__ __launch_bounds__(256) void kDet(const ushort_t* __restrict__ f,
                                            int* __restrict__ flag)
{
    __shared__ int bad, zc;
    if (threadIdx.x == 0) { bad = 0; zc = 0; }
    __syncthreads();
    int myz = 0;
    for (int i = threadIdx.x; i < 4096; i += 256) {
        ushort_t v = f[i];
        int e = (v >> 7) & 0xff;
        if (e >= 140) bad = 1;
        if ((i & 1) == 0 && v == 0) myz++;
    }
    atomicAdd(&zc, myz);
    __syncthreads();
    if (threadIdx.x == 0) *flag = (bad || zc > 1024) ? 0 : 1;   // 1 = bf16
}

// ---------------------------------------------------------------------------
// kA: per batch b: timestep emb -> t_h -> y -> q0 -> q[b,128]; zero w,l.
template<bool BF16>
__device__ void kA_impl(
    const void* y_t, const int* t,
    const void* Wt, const void* bt, const void* Win, const void* bin_,
    const void* Wq, const void* bq, const void* Wiq, const void* biq,
    float* q_out, float* w_zero, float* l_zero)
{
    using L = Ld<BF16>;
    int b = blockIdx.x, tid = threadIdx.x;
    __shared__ float emb[64];
    __shared__ float y[HID];
    __shared__ float q0[CENC];

    for (int i = tid; i < 512; i += 128) w_zero[b * 512 + i] = 0.f;
    if (tid < 4) l_zero[b * 4 + tid] = 0.f;

    if (tid < 32) {
        float fr = __expf(-(float)tid * 0.28782313662425576f); // ln(1e4)/32
        float arg = (float)t[b] * fr;
        emb[tid]      = sinf(arg);
        emb[tid + 32] = cosf(arg);
    }
    __syncthreads();

    float yt0 = L::at(y_t, b*3+0), yt1 = L::at(y_t, b*3+1), yt2 = L::at(y_t, b*3+2);
    for (int o = tid; o < HID; o += 128) {
        float acc = L::at(bt, o);
        for (int k = 0; k < 64; k++) acc += emb[k] * L::at(Wt, k * HID + o);
        float th = fmaxf(acc, 0.f);
        y[o] = L::at(bin_, o) + yt0 * L::at(Win, o) + yt1 * L::at(Win, HID + o)
             + yt2 * L::at(Win, 2 * HID + o) + th;
    }
    __syncthreads();

    {
        float acc = L::at(bq, tid);
        for (int k = 0; k < HID; k++) acc += y[k] * L::at(Wq, k * CENC + tid);
        q0[tid] = acc;
    }
    __syncthreads();
    {
        float acc = L::at(biq, tid);
        for (int k = 0; k < CENC; k++) acc += q0[k] * L::at(Wiq, k * CENC + tid);
        q_out[b * CENC + tid] = acc;
    }
}

__global__ __launch_bounds__(128) void kA(
    const int* __restrict__ flag,
    const void* y_t, const int* t,
    const void* Wt, const void* bt, const void* Win, const void* bin_,
    const void* Wq, const void* bq, const void* Wiq, const void* biq,
    float* q_out, float* w_zero, float* l_zero)
{
    if (*flag) kA_impl<true >(y_t,t,Wt,bt,Win,bin_,Wq,bq,Wiq,biq,q_out,w_zero,l_zero);
    else       kA_impl<false>(y_t,t,Wt,bt,Win,bin_,Wq,bq,Wiq,biq,q_out,w_zero,l_zero);
}

// ---------------------------------------------------------------------------
// kB: per (b,h): u[b,h,:] = Wtok@(Wk@(Wik[:,hblk]@q_h)) * rsqrt(32)
//     cq[b,h]  = ((btok@Wk+bk).(Wik[:,hblk]@q_h) + bik[hblk].q_h) * rsqrt(32)
template<bool BF16>
__device__ void kB_impl(
    const float* q,
    const void* Wtok, const void* btok, const void* Wk, const void* bk,
    const void* Wik, const void* bik,
    float* u_out, float* cq_out)
{
    using L = Ld<BF16>;
    int blk = blockIdx.x, b = blk >> 2, h = blk & 3, tid = threadIdx.x;
    __shared__ float qh[32];
    __shared__ float g[CENC];
    __shared__ float a1[CENC];
    __shared__ float red[128];

    if (tid < 32) qh[tid] = q[b * CENC + h * 32 + tid];
    __syncthreads();

    float tmp = L::at(bk, tid);
    for (int c1 = 0; c1 < CENC; c1++) tmp += L::at(btok, c1) * L::at(Wk, c1 * CENC + tid);

    float gg = 0.f;
    #pragma unroll
    for (int j = 0; j < 4; j++) {
        float r[8]; L::v8(Wik, tid * CENC + h * 32 + j * 8, r);
        const float* qv = &qh[j * 8];
        #pragma unroll
        for (int m = 0; m < 8; m++) gg += r[m] * qv[m];
    }
    g[tid] = gg;
    red[tid] = tmp * gg + (tid < 32 ? L::at(bik, h * 32 + tid) * qh[tid] : 0.f);
    __syncthreads();
    for (int s = 64; s > 0; s >>= 1) { if (tid < s) red[tid] += red[tid + s]; __syncthreads(); }
    if (tid == 0) cq_out[b * 4 + h] = red[0] * RSQRT32;

    float a = 0.f;
    #pragma unroll
    for (int j = 0; j < 16; j++) {
        float r[8]; L::v8(Wk, tid * CENC + j * 8, r);
        const float* gv = &g[j * 8];
        #pragma unroll
        for (int m = 0; m < 8; m++) a += r[m] * gv[m];
    }
    a1[tid] = a;
    __syncthreads();

    float uu = 0.f;
    #pragma unroll
    for (int j = 0; j < 16; j++) {
        float r[8]; L::v8(Wtok, tid * CENC + j * 8, r);
        const float* av = &a1[j * 8];
        #pragma unroll
        for (int m = 0; m < 8; m++) uu += r[m] * av[m];
    }
    u_out[(b * 4 + h) * CENC + tid] = uu * RSQRT32;
}

__global__ __launch_bounds__(128) void kB(
    const int* __restrict__ flag, const float* q,
    const void* Wtok, const void* btok, const void* Wk, const void* bk,
    const void* Wik, const void* bik, float* u_out, float* cq_out)
{
    if (*flag) kB_impl<true >(q,Wtok,btok,Wk,bk,Wik,bik,u_out,cq_out);
    else       kB_impl<false>(q,Wtok,btok,Wk,bk,Wik,bik,u_out,cq_out);
}

// ---------------------------------------------------------------------------
// kF: fused streaming pass. 256 thr, 128 tokens/block, 2 chunks of 64.
//  Phase 1: 16 groups x 16 lanes; group owns 4 tokens/chunk; lane owns 8 ch.
//    u in registers per sorted-batch segment; shfl_xor(16) reduce; lane 0
//    writes e=exp(min(score,30)) to LDS, accumulates l (atomic per segment).
//  Phase 2: 2 subgroups x 128 lanes (lane=channel, coalesced re-read);
//    acc[h] += e*f per segment, atomic flush to w.
template<bool BF16>
__device__ void kF_impl(
    const void* features, const int* batch_idx,
    const float* u, const float* cq, float* w, float* l)
{
    using L = Ld<BF16>;
    int base = blockIdx.x * 128;
    int tau = threadIdx.x;
    __shared__ int lb[128];
    __shared__ float eL[64][4];

    if (tau < 128) lb[tau] = batch_idx[base + tau];
    __syncthreads();

    int qq = tau & 15, grp = tau >> 4;
    float uu[4][8], cqr[4], lacc[4] = {0.f, 0.f, 0.f, 0.f};
    int cur1 = -1;

    int c = tau & 127, sg = tau >> 7;
    float acc[4] = {0.f, 0.f, 0.f, 0.f};
    int cur2 = -1;

    #pragma unroll 1
    for (int chunk = 0; chunk < 2; chunk++) {
        int cbase = chunk * 64;

        // ---- phase 1 ----
        #pragma unroll
        for (int j = 0; j < 4; j++) {
            int tok = cbase + grp * 4 + j;
            int b = lb[tok];
            if (b != cur1) {
                if (cur1 >= 0 && qq == 0) {
                    #pragma unroll
                    for (int h = 0; h < 4; h++) atomicAdd(&l[cur1 * 4 + h], lacc[h]);
                }
                #pragma unroll
                for (int h = 0; h < 4; h++) {
                    const float4* up = (const float4*)(u + ((b << 2) + h) * CENC + (qq << 3));
                    float4 u0 = up[0], u1 = up[1];
                    uu[h][0]=u0.x; uu[h][1]=u0.y; uu[h][2]=u0.z; uu[h][3]=u0.w;
                    uu[h][4]=u1.x; uu[h][5]=u1.y; uu[h][6]=u1.z; uu[h][7]=u1.w;
                    cqr[h] = cq[(b << 2) + h];
                    lacc[h] = 0.f;
                }
                cur1 = b;
            }
            float f[8];
            L::v8(features, (long)(base + tok) * CENC + (qq << 3), f);
            float p[4];
            #pragma unroll
            for (int h = 0; h < 4; h++) {
                p[h] = f[0]*uu[h][0] + f[1]*uu[h][1] + f[2]*uu[h][2] + f[3]*uu[h][3]
                     + f[4]*uu[h][4] + f[5]*uu[h][5] + f[6]*uu[h][6] + f[7]*uu[h][7];
            }
            #pragma unroll
            for (int m = 1; m < 16; m <<= 1) {
                #pragma unroll
                for (int h = 0; h < 4; h++) p[h] += __shfl_xor(p[h], m, 16);
            }
            if (qq == 0) {
                #pragma unroll
                for (int h = 0; h < 4; h++) {
                    float e = __expf(fminf(p[h] + cqr[h], 30.f));
                    eL[tok - cbase][h] = e;
                    lacc[h] += e;
                }
            }
        }
        __syncthreads();

        // ---- phase 2 ----
        #pragma unroll 1
        for (int i = 0; i < 32; i++) {
            int tic = sg * 32 + i;
            int tok = cbase + tic;
            int b = lb[tok];
            if (b != cur2) {
                if (cur2 >= 0) {
                    #pragma unroll
                    for (int h = 0; h < 4; h++) {
                        atomicAdd(&w[(cur2 * 4 + h) * CENC + c], acc[h]);
                        acc[h] = 0.f;
                    }
                }
                cur2 = b;
            }
            float fv = L::at(features, (long)(base + tok) * CENC + c);
            #pragma unroll
            for (int h = 0; h < 4; h++) acc[h] += eL[tic][h] * fv;
        }
        __syncthreads();
    }

    if (cur1 >= 0 && qq == 0) {
        #pragma unroll
        for (int h = 0; h < 4; h++) atomicAdd(&l[cur1 * 4 + h], lacc[h]);
    }
    if (cur2 >= 0) {
        #pragma unroll
        for (int h = 0; h < 4; h++) atomicAdd(&w[(cur2 * 4 + h) * CENC + c], acc[h]);
    }
}

__global__ __launch_bounds__(256) void kF(
    const int* __restrict__ flag,
    const void* features, const int* batch_idx,
    const float* u, const float* cq, float* w, float* l)
{
    if (*flag) kF_impl<true >(features, batch_idx, u, cq, w, l);
    else       kF_impl<false>(features, batch_idx, u, cq, w, l);
}

// ---------------------------------------------------------------------------
// kE: per batch: wbar=w/l -> ctx -> attn_out -> y2 -> out (dtype-matched).
template<bool BF16>
__device__ void kE_impl(
    const float* w, const float* l,
    const void* Wtok, const void* btok, const void* Wv, const void* bv,
    const void* Wiv, const void* biv, const void* Wo, const void* bo,
    const void* Wco, const void* bco, const void* Wout, const void* bout,
    void* out)
{
    using L = Ld<BF16>;
    int b = blockIdx.x, tid = threadIdx.x;
    __shared__ float wb[4][CENC];
    __shared__ float buf1[CENC], buf2[CENC];
    __shared__ float ctx[CENC];
    __shared__ float ao[CENC];
    __shared__ float y2[HID];
    __shared__ float red[128];

    #pragma unroll
    for (int h = 0; h < 4; h++) {
        float lv = l[b * 4 + h];
        float inv = (lv > 1e-30f) ? 1.f / lv : 0.f;
        wb[h][tid] = w[(b * 4 + h) * CENC + tid] * inv;
    }
    __syncthreads();

    for (int h = 0; h < 4; h++) {
        float a = L::at(btok, tid);
        for (int k = 0; k < CENC; k++) a += wb[h][k] * L::at(Wtok, k * CENC + tid);
        buf1[tid] = a;
        __syncthreads();
        float a2 = L::at(bv, tid);
        for (int k = 0; k < CENC; k++) a2 += buf1[k] * L::at(Wv, k * CENC + tid);
        buf2[tid] = a2;
        __syncthreads();
        if (tid < 32) {
            float cc = L::at(biv, h * 32 + tid);
            for (int k = 0; k < CENC; k++) cc += buf2[k] * L::at(Wiv, k * CENC + h * 32 + tid);
            ctx[h * 32 + tid] = cc;
        }
        __syncthreads();
    }

    float aoo = L::at(bo, tid);
    for (int k = 0; k < CENC; k++) aoo += ctx[k] * L::at(Wo, k * CENC + tid);
    ao[tid] = aoo;
    __syncthreads();

    for (int o = tid; o < HID; o += 128) {
        float a = L::at(bco, o);
        for (int k = 0; k < CENC; k++) a += ao[k] * L::at(Wco, k * HID + o);
        y2[o] = a;
    }
    __syncthreads();

    for (int o = 0; o < 3; o++) {
        float p = 0.f;
        for (int k = tid; k < HID; k += 128) p += y2[k] * L::at(Wout, k * 3 + o);
        red[tid] = p; __syncthreads();
        for (int s = 64; s > 0; s >>= 1) { if (tid < s) red[tid] += red[tid + s]; __syncthreads(); }
        if (tid == 0) {
            float val = red[0] + L::at(bout, o);
            if (BF16) ((ushort_t*)out)[b * 3 + o] = f2bf(val);
            else      ((float*)out)[b * 3 + o] = val;
        }
        __syncthreads();
    }
}

__global__ __launch_bounds__(128) void kE(
    const int* __restrict__ flag,
    const float* w, const float* l,
    const void* Wtok, const void* btok, const void* Wv, const void* bv,
    const void* Wiv, const void* biv, const void* Wo, const void* bo,
    const void* Wco, const void* bco, const void* Wout, const void* bout,
    void* out)
{
    if (*flag) kE_impl<true >(w,l,Wtok,btok,Wv,bv,Wiv,biv,Wo,bo,Wco,bco,Wout,bout,out);
    else       kE_impl<false>(w,l,Wtok,btok,Wv,bv,Wiv,biv,Wo,bo,Wco,bco,Wout,bout,out);
}

// ---------------------------------------------------------------------------
extern "C" void kernel_launch(void* const* d_in, const int* in_sizes, int n_in,
                              void* d_out, int out_size, void* d_ws, size_t ws_size,
                              hipStream_t stream)
{
    const void* features = d_in[0];
    const int*  batch_idx= (const int*)d_in[1];
    const void* y_t      = d_in[2];
    const int*  t        = (const int*)d_in[3];
    // d_in[4] = N_max (unused)
    const void *Wtok=d_in[5],  *btok=d_in[6];
    const void *Wt  =d_in[7],  *bt  =d_in[8];
    const void *Win =d_in[9],  *bin_=d_in[10];
    const void *Wq  =d_in[11], *bq  =d_in[12];
    const void *Wk  =d_in[13], *bk  =d_in[14];
    const void *Wv  =d_in[15], *bv  =d_in[16];
    const void *Wiq =d_in[17], *biq =d_in[18];
    const void *Wik =d_in[19], *bik =d_in[20];
    const void *Wiv =d_in[21], *biv =d_in[22];
    const void *Wo  =d_in[23], *bo  =d_in[24];
    const void *Wco =d_in[25], *bco =d_in[26];
    const void *Wout=d_in[27], *bout=d_in[28];

    int N = in_sizes[0] / CENC;   // 131072

    float* ws = (float*)d_ws;
    int*   flag = (int*)ws;        // ws[0]
    float* q  = ws + 64;           // 8192
    float* u  = ws + 64 + 8192;    // 32768
    float* cq = ws + 64 + 40960;   // 256
    float* l  = ws + 64 + 41216;   // 256
    float* w  = ws + 64 + 41472;   // 32768 -> total 74304 floats = 297 KB

    kDet<<<1, 256, 0, stream>>>((const ushort_t*)features, flag);
    kA<<<NB, 128, 0, stream>>>(flag, y_t, t, Wt, bt, Win, bin_, Wq, bq, Wiq, biq, q, w, l);
    kB<<<NB * 4, 128, 0, stream>>>(flag, q, Wtok, btok, Wk, bk, Wik, bik, u, cq);
    kF<<<N / 128, 256, 0, stream>>>(flag, features, batch_idx, u, cq, w, l);
    kE<<<NB, 128, 0, stream>>>(flag, w, l, Wtok, btok, Wv, bv, Wiv, biv, Wo, bo,
                               Wco, bco, Wout, bout, d_out);
}

// Round 4
// 221.819 us; speedup vs baseline: 1.9664x; 1.9664x over previous
//
#include <hip/hip_runtime.h>
#include <hip/hip_bf16.h>

// SparseDiffusionModel on MI355X — dtype-adaptive (fp32 or bf16 inputs).
//
// Algebra: everything between `features` and attention is affine in features,
// and the query is one token/batch:
//   score[i,h] = f_i . u[b,h] + cq[b,h]
//     u[b,h,:] = UA[:,hblk] @ q_h / sqrt(32),   UA = Wtok@Wk@Wik  (precomputed)
//     cq[b,h]  = cv[hblk] . q_h / sqrt(32),     cv = (btok@Wk+bk)@Wik + bik
//   ctx[b,hblk] = wbar_h @ VA[:,hblk] + dv[hblk],  VA = Wtok@Wv@Wiv,
//     dv = (btok@Wv+bv)@Wiv + biv,   wbar = softmax-weighted feature mean.
// => ONE streaming pass over features + tiny per-batch GEMMs.
//
// Round-3 postmortem: kF spilled its uu[4][8] register array to scratch
// (VGPR_Count=40 < ~70 live) -> 176us at 3% HBM. This version uses only named
// float4 registers, an LDS bf16 tile (single global read), and precomputed
// weight products so the small kernels shrink.
//
// ws (floats): flag@0 | u@64 [32768] | cq [256] | l [256] | w [32768]
//              | UAt [16384] | VA [16384] | cv [128] | dv [128]  (~388 KB)

typedef unsigned short ushort_t;
typedef unsigned int uint_t;
typedef unsigned long long ull_t;

#define NB 64
#define CENC 128
#define HID 512
#define RSQRT32 0.17677669529663689f

__device__ __forceinline__ float blo(uint_t u){ return __uint_as_float(u << 16); }
__device__ __forceinline__ float bhi(uint_t u){ return __uint_as_float(u & 0xffff0000u); }
__device__ __forceinline__ float bf2f(ushort_t h){ return __uint_as_float(((uint_t)h) << 16); }
__device__ __forceinline__ ushort_t f2bf(float f){
    uint_t u = __float_as_uint(f);
    u += 0x7fffu + ((u >> 16) & 1u);   // RNE
    return (ushort_t)(u >> 16);
}

template<bool BF16> struct Ld;
template<> struct Ld<true> {
    static __device__ __forceinline__ float at(const void* p, long i) {
        return __uint_as_float(((uint_t)((const ushort_t*)p)[i]) << 16);
    }
};
template<> struct Ld<false> {
    static __device__ __forceinline__ float at(const void* p, long i) {
        return ((const float*)p)[i];
    }
};

// ---------------------------------------------------------------------------
// kPre: per-block dtype detection + one-time weight products.
// blocks 0..127: UAt (UA row c, stored transposed UAt[j*128+c])
// blocks 128..255: VA row c. block 256: cv. block 257: dv.
template<bool BF16>
__device__ void kPre_impl(
    const void* Wtok, const void* btok,
    const void* Wk, const void* bk, const void* Wik, const void* bik,
    const void* Wv, const void* bv, const void* Wiv, const void* biv,
    float* UAt, float* VA, float* cv, float* dv, float* tmp)
{
    using L = Ld<BF16>;
    int blk = blockIdx.x, tid = threadIdx.x;   // 128 threads
    if (blk < 128) {
        int cx = blk;
        float a = 0.f;
        for (int k = 0; k < 128; k++) a += L::at(Wtok, cx*128+k) * L::at(Wk, k*128+tid);
        tmp[tid] = a; __syncthreads();
        float o = 0.f;
        for (int k = 0; k < 128; k++) o += tmp[k] * L::at(Wik, k*128+tid);
        UAt[tid*128 + cx] = o;
    } else if (blk < 256) {
        int cx = blk - 128;
        float a = 0.f;
        for (int k = 0; k < 128; k++) a += L::at(Wtok, cx*128+k) * L::at(Wv, k*128+tid);
        tmp[tid] = a; __syncthreads();
        float o = 0.f;
        for (int k = 0; k < 128; k++) o += tmp[k] * L::at(Wiv, k*128+tid);
        VA[cx*128 + tid] = o;
    } else if (blk == 256) {
        float a = L::at(bk, tid);
        for (int k = 0; k < 128; k++) a += L::at(btok, k) * L::at(Wk, k*128+tid);
        tmp[tid] = a; __syncthreads();
        float o = L::at(bik, tid);
        for (int k = 0; k < 128; k++) o += tmp[k] * L::at(Wik, k*128+tid);
        cv[tid] = o;
    } else {
        float a = L::at(bv, tid);
        for (int k = 0; k < 128; k++) a += L::at(btok, k) * L::at(Wv, k*128+tid);
        tmp[tid] = a; __syncthreads();
        float o = L::at(biv, tid);
        for (int k = 0; k < 128; k++) o += tmp[k] * L::at(Wiv, k*128+tid);
        dv[tid] = o;
    }
}

__global__ __launch_bounds__(128) void kPre(
    const ushort_t* __restrict__ fraw,
    const void* Wtok, const void* btok,
    const void* Wk, const void* bk, const void* Wik, const void* bik,
    const void* Wv, const void* bv, const void* Wiv, const void* biv,
    int* flag_out, float* UAt, float* VA, float* cv, float* dv)
{
    __shared__ int sbad, szc;
    __shared__ float tmp[128];
    int tid = threadIdx.x;
    if (tid == 0) { sbad = 0; szc = 0; }
    __syncthreads();
    int myb = 0, myz = 0;
    for (int i = tid; i < 4096; i += 128) {
        ushort_t v = fraw[i];
        if (((v >> 7) & 0xff) >= 140) myb = 1;
        if (!(i & 1) && v == 0) myz++;
    }
    if (myb) atomicOr(&sbad, 1);
    atomicAdd(&szc, myz);
    __syncthreads();
    int flag = (sbad || szc > 1024) ? 0 : 1;     // 1 = true bf16
    if (blockIdx.x == 0 && tid == 0) *flag_out = flag;
    if (flag) kPre_impl<true >(Wtok,btok,Wk,bk,Wik,bik,Wv,bv,Wiv,biv,UAt,VA,cv,dv,tmp);
    else      kPre_impl<false>(Wtok,btok,Wk,bk,Wik,bik,Wv,bv,Wiv,biv,UAt,VA,cv,dv,tmp);
}

// ---------------------------------------------------------------------------
// kA: per batch: zero w,l; emb -> y -> q0 -> q -> u (via UAt), cq (via cv).
// 256 threads: 2-way k-split on the 512-deep loops.
template<bool BF16>
__device__ void kA_impl(
    const void* y_t, const int* t,
    const void* Wt, const void* bt, const void* Win, const void* bin_,
    const void* Wq, const void* bq, const void* Wiq, const void* biq,
    const float* UAt, const float* cv,
    float* u_out, float* cq_out, float* wz, float* lz, float* sh)
{
    using L = Ld<BF16>;
    float* emb = sh;          // 64
    float* y   = sh + 64;     // 512
    float* p2  = sh + 576;    // 256
    float* q0  = sh + 832;    // 128
    float* qL  = sh + 960;    // 128
    int b = blockIdx.x, tid = threadIdx.x;
    int tid2 = tid & 127, half = tid >> 7;

    for (int i = tid; i < 512; i += 256) wz[b*512 + i] = 0.f;
    if (tid < 4) lz[b*4 + tid] = 0.f;

    if (tid < 32) {
        float fr = __expf(-(float)tid * 0.28782313662425576f); // ln(1e4)/32
        float arg = (float)t[b] * fr;
        emb[tid]      = sinf(arg);
        emb[tid + 32] = cosf(arg);
    }
    __syncthreads();

    float yt0 = L::at(y_t, b*3+0), yt1 = L::at(y_t, b*3+1), yt2 = L::at(y_t, b*3+2);
    for (int rep = 0; rep < 2; rep++) {
        int o = tid + rep*256;
        float acc = L::at(bt, o);
        for (int k = 0; k < 64; k++) acc += emb[k] * L::at(Wt, k*512+o);
        acc = fmaxf(acc, 0.f);
        y[o] = acc + L::at(bin_, o) + yt0*L::at(Win, o) + yt1*L::at(Win, 512+o)
             + yt2*L::at(Win, 1024+o);
    }
    __syncthreads();
    {
        float acc = 0.f;
        for (int k = half*256; k < half*256+256; k++) acc += y[k] * L::at(Wq, k*128+tid2);
        p2[half*128 + tid2] = acc;
    }
    __syncthreads();
    if (tid < 128) q0[tid] = p2[tid] + p2[128+tid] + L::at(bq, tid);
    __syncthreads();
    {
        float acc = 0.f;
        for (int k = half*64; k < half*64+64; k++) acc += q0[k] * L::at(Wiq, k*128+tid2);
        p2[half*128 + tid2] = acc;
    }
    __syncthreads();
    if (tid < 128) qL[tid] = p2[tid] + p2[128+tid] + L::at(biq, tid);
    __syncthreads();
    // u[b,h,c] = (sum_j UAt[(h*32+j)*128+c] * qL[h*32+j]) / sqrt(32)
    for (int h = half*2; h < half*2+2; h++) {
        float acc = 0.f;
        for (int j = 0; j < 32; j++) acc += UAt[(h*32+j)*128 + tid2] * qL[h*32+j];
        u_out[b*512 + h*128 + tid2] = acc * RSQRT32;
    }
    if (tid < 4) {
        float acc = 0.f;
        for (int j = 0; j < 32; j++) acc += cv[tid*32+j] * qL[tid*32+j];
        cq_out[b*4 + tid] = acc * RSQRT32;
    }
}

__global__ __launch_bounds__(256) void kA(
    const int* __restrict__ flag,
    const void* y_t, const int* t,
    const void* Wt, const void* bt, const void* Win, const void* bin_,
    const void* Wq, const void* bq, const void* Wiq, const void* biq,
    const float* UAt, const float* cv,
    float* u_out, float* cq_out, float* wz, float* lz)
{
    __shared__ float sh[1088];
    if (*flag) kA_impl<true >(y_t,t,Wt,bt,Win,bin_,Wq,bq,Wiq,biq,UAt,cv,u_out,cq_out,wz,lz,sh);
    else       kA_impl<false>(y_t,t,Wt,bt,Win,bin_,Wq,bq,Wiq,biq,UAt,cv,u_out,cq_out,wz,lz,sh);
}

// ---------------------------------------------------------------------------
// kF: fused streaming pass. 256 thr, 128 tokens/block, LDS bf16 tile.
//  - staging: one coalesced global read (fp32->bf16 RNE or raw bf16)
//  - segment starts via ballot+popcount ranks (sorted batch_idx)
//  - phase 1: 16 groups x 16 lanes; u in 8 named float4 regs per segment
//    (NO arrays -> no scratch spill); shfl_xor(16) reduce; e -> eL, l atomics
//  - phase 2: lane=channel column reads from tile (2 lanes/word, conflict-free)
struct alignas(16) KFS {
    ushort_t tile[128*136];    // 34816 B, row stride 136 breaks pow-2 banks
    float eL[128*4];
    int lb[128];
    int starts[65];
    ull_t smask[2];
    int nseg;
};

__global__ __launch_bounds__(256, 4) void kF(
    const int* __restrict__ flag_p,
    const void* __restrict__ features, const int* __restrict__ batch_idx,
    const float* __restrict__ u, const float* __restrict__ cq,
    float* __restrict__ w, float* __restrict__ l)
{
    extern __shared__ char smemraw[];
    KFS* S = (KFS*)smemraw;
    const int base = blockIdx.x * 128;
    const int tau = threadIdx.x;

    if (*flag_p) {               // bf16 input: raw copy
        const ushort_t* src = (const ushort_t*)features + (size_t)base * 128;
        #pragma unroll
        for (int s = 0; s < 8; s++) {
            int idx = s * 256 + tau;         // uint4 index
            int ui = idx * 8;
            int tok = ui >> 7, ch = ui & 127;
            uint4 v = ((const uint4*)src)[idx];
            *(uint4*)&S->tile[tok*136 + ch] = v;
        }
    } else {                     // fp32 input: convert to bf16 (RNE)
        const float* src = (const float*)features + (size_t)base * 128;
        #pragma unroll
        for (int s = 0; s < 16; s++) {
            int idx = s * 256 + tau;         // float4 index
            int fi = idx * 4;
            int tok = fi >> 7, ch = fi & 127;
            float4 v = ((const float4*)src)[idx];
            uint_t lo = (uint_t)f2bf(v.x) | ((uint_t)f2bf(v.y) << 16);
            uint_t hi = (uint_t)f2bf(v.z) | ((uint_t)f2bf(v.w) << 16);
            *(uint2*)&S->tile[tok*136 + ch] = make_uint2(lo, hi);
        }
    }
    if (tau < 128) S->lb[tau] = batch_idx[base + tau];
    __syncthreads();

    bool isstart = (tau < 128) && (tau == 0 || S->lb[tau] != S->lb[tau-1]);
    ull_t m = __ballot(isstart);
    int wv = tau >> 6, lane = tau & 63;
    if (wv < 2 && lane == 0) S->smask[wv] = m;
    __syncthreads();
    if (isstart) {
        int rank = ((wv == 1) ? __popcll(S->smask[0]) : 0)
                 + __popcll(m & ((1ull << lane) - 1ull));
        S->starts[rank] = tau;
    }
    if (tau == 0) S->nseg = __popcll(S->smask[0]) + __popcll(S->smask[1]);
    __syncthreads();

    const int qq = tau & 15, grp = tau >> 4;
    const int c = tau & 127, sg = tau >> 7;
    const int nseg = S->nseg;

    for (int s = 0; s < nseg; s++) {
        const int lo = S->starts[s];
        const int hi = (s + 1 < nseg) ? S->starts[s+1] : 128;
        const int b = S->lb[lo];

        const float* ub = u + b*512 + qq*8;       // L2-hot, named regs only
        float4 u0a = *(const float4*)(ub + 0),   u0b = *(const float4*)(ub + 4);
        float4 u1a = *(const float4*)(ub + 128), u1b = *(const float4*)(ub + 132);
        float4 u2a = *(const float4*)(ub + 256), u2b = *(const float4*)(ub + 260);
        float4 u3a = *(const float4*)(ub + 384), u3b = *(const float4*)(ub + 388);
        float4 cqr = *(const float4*)(cq + b*4);

        float l0=0.f, l1=0.f, l2=0.f, l3=0.f;
        for (int tok = lo + grp; tok < hi; tok += 16) {
            uint4 fv = *(const uint4*)&S->tile[tok*136 + qq*8];
            float f0=blo(fv.x), f1=bhi(fv.x), f2=blo(fv.y), f3=bhi(fv.y);
            float f4=blo(fv.z), f5=bhi(fv.z), f6=blo(fv.w), f7=bhi(fv.w);
            float p0 = f0*u0a.x+f1*u0a.y+f2*u0a.z+f3*u0a.w+f4*u0b.x+f5*u0b.y+f6*u0b.z+f7*u0b.w;
            float p1 = f0*u1a.x+f1*u1a.y+f2*u1a.z+f3*u1a.w+f4*u1b.x+f5*u1b.y+f6*u1b.z+f7*u1b.w;
            float p2 = f0*u2a.x+f1*u2a.y+f2*u2a.z+f3*u2a.w+f4*u2b.x+f5*u2b.y+f6*u2b.z+f7*u2b.w;
            float p3 = f0*u3a.x+f1*u3a.y+f2*u3a.z+f3*u3a.w+f4*u3b.x+f5*u3b.y+f6*u3b.z+f7*u3b.w;
            #pragma unroll
            for (int mm = 1; mm < 16; mm <<= 1) {
                p0 += __shfl_xor(p0, mm, 16);
                p1 += __shfl_xor(p1, mm, 16);
                p2 += __shfl_xor(p2, mm, 16);
                p3 += __shfl_xor(p3, mm, 16);
            }
            if (qq == 0) {
                float e0 = __expf(fminf(p0 + cqr.x, 30.f));
                float e1 = __expf(fminf(p1 + cqr.y, 30.f));
                float e2 = __expf(fminf(p2 + cqr.z, 30.f));
                float e3 = __expf(fminf(p3 + cqr.w, 30.f));
                *(float4*)&S->eL[tok*4] = make_float4(e0, e1, e2, e3);
                l0 += e0; l1 += e1; l2 += e2; l3 += e3;
            }
        }
        if (qq == 0) {
            atomicAdd(&l[b*4+0], l0); atomicAdd(&l[b*4+1], l1);
            atomicAdd(&l[b*4+2], l2); atomicAdd(&l[b*4+3], l3);
        }
        __syncthreads();   // eL ready (only barrier per segment; regions disjoint)

        float a0=0.f, a1=0.f, a2=0.f, a3=0.f;
        for (int tok = lo + sg; tok < hi; tok += 2) {
            float fvv = bf2f(S->tile[tok*136 + c]);
            float4 e = *(const float4*)&S->eL[tok*4];
            a0 += e.x*fvv; a1 += e.y*fvv; a2 += e.z*fvv; a3 += e.w*fvv;
        }
        atomicAdd(&w[b*512 +   0 + c], a0);
        atomicAdd(&w[b*512 + 128 + c], a1);
        atomicAdd(&w[b*512 + 256 + c], a2);
        atomicAdd(&w[b*512 + 384 + c], a3);
    }
}

// ---------------------------------------------------------------------------
// kE: per batch: wbar=w/l -> ctx (via VA,dv) -> ao -> y2 -> out.
template<bool BF16>
__device__ void kE_impl(
    const float* w, const float* l, const float* VA, const float* dv,
    const void* Wo, const void* bo, const void* Wco, const void* bco,
    const void* Wout, const void* bout, void* out, float* sh)
{
    using L = Ld<BF16>;
    float* wb  = sh;           // 512 [h*128+c]
    float* p2  = sh + 512;     // 256
    float* ctx = sh + 768;     // 128
    float* ao  = sh + 896;     // 128
    float* y2  = sh + 1024;    // 512
    float* red = sh + 1536;    // 256
    int b = blockIdx.x, tid = threadIdx.x;
    int tid2 = tid & 127, half = tid >> 7;

    for (int i = tid; i < 512; i += 256) {
        float lv = l[b*4 + (i >> 7)];
        float inv = (lv > 1e-30f) ? 1.f/lv : 0.f;
        wb[i] = w[b*512 + i] * inv;
    }
    __syncthreads();
    {   // ctx[col] = dv[col] + sum_c wb[h(col)*128+c] * VA[c*128+col]
        int h = tid2 >> 5;
        float acc = 0.f;
        for (int k = half*64; k < half*64+64; k++) acc += wb[h*128 + k] * VA[k*128 + tid2];
        p2[half*128 + tid2] = acc;
    }
    __syncthreads();
    if (tid < 128) ctx[tid] = p2[tid] + p2[128+tid] + dv[tid];
    __syncthreads();
    {
        float acc = 0.f;
        for (int k = half*64; k < half*64+64; k++) acc += ctx[k] * L::at(Wo, k*128+tid2);
        p2[half*128 + tid2] = acc;
    }
    __syncthreads();
    if (tid < 128) ao[tid] = p2[tid] + p2[128+tid] + L::at(bo, tid);
    __syncthreads();
    for (int rep = 0; rep < 2; rep++) {
        int o = tid + rep*256;
        float acc = L::at(bco, o);
        for (int k = 0; k < 128; k++) acc += ao[k] * L::at(Wco, k*512+o);
        y2[o] = acc;
    }
    __syncthreads();
    for (int o = 0; o < 3; o++) {
        float p = y2[tid]*L::at(Wout, tid*3+o) + y2[tid+256]*L::at(Wout, (tid+256)*3+o);
        red[tid] = p; __syncthreads();
        for (int st = 128; st > 0; st >>= 1) { if (tid < st) red[tid] += red[tid+st]; __syncthreads(); }
        if (tid == 0) {
            float val = red[0] + L::at(bout, o);
            if (BF16) ((ushort_t*)out)[b*3+o] = f2bf(val);
            else      ((float*)out)[b*3+o] = val;
        }
        __syncthreads();
    }
}

__global__ __launch_bounds__(256) void kE(
    const int* __restrict__ flag,
    const float* w, const float* l, const float* VA, const float* dv,
    const void* Wo, const void* bo, const void* Wco, const void* bco,
    const void* Wout, const void* bout, void* out)
{
    __shared__ float sh[1792];
    if (*flag) kE_impl<true >(w,l,VA,dv,Wo,bo,Wco,bco,Wout,bout,out,sh);
    else       kE_impl<false>(w,l,VA,dv,Wo,bo,Wco,bco,Wout,bout,out,sh);
}

// ---------------------------------------------------------------------------
extern "C" void kernel_launch(void* const* d_in, const int* in_sizes, int n_in,
                              void* d_out, int out_size, void* d_ws, size_t ws_size,
                              hipStream_t stream)
{
    const void* features = d_in[0];
    const int*  batch_idx= (const int*)d_in[1];
    const void* y_t      = d_in[2];
    const int*  t        = (const int*)d_in[3];
    // d_in[4] = N_max (unused)
    const void *Wtok=d_in[5],  *btok=d_in[6];
    const void *Wt  =d_in[7],  *bt  =d_in[8];
    const void *Win =d_in[9],  *bin_=d_in[10];
    const void *Wq  =d_in[11], *bq  =d_in[12];
    const void *Wk  =d_in[13], *bk  =d_in[14];
    const void *Wv  =d_in[15], *bv  =d_in[16];
    const void *Wiq =d_in[17], *biq =d_in[18];
    const void *Wik =d_in[19], *bik =d_in[20];
    const void *Wiv =d_in[21], *biv =d_in[22];
    const void *Wo  =d_in[23], *bo  =d_in[24];
    const void *Wco =d_in[25], *bco =d_in[26];
    const void *Wout=d_in[27], *bout=d_in[28];

    int N = in_sizes[0] / CENC;   // 131072

    float* ws = (float*)d_ws;
    int*   flag = (int*)ws;            // ws[0]
    float* u   = ws + 64;              // 32768
    float* cqv = ws + 64 + 32768;      // 256
    float* l   = ws + 64 + 33024;      // 256
    float* w   = ws + 64 + 33280;      // 32768
    float* UAt = ws + 64 + 66048;      // 16384
    float* VA  = ws + 64 + 82432;      // 16384
    float* cv  = ws + 64 + 98816;      // 128
    float* dv  = ws + 64 + 98944;      // 128  -> total ~388 KB

    kPre<<<258, 128, 0, stream>>>((const ushort_t*)features,
        Wtok, btok, Wk, bk, Wik, bik, Wv, bv, Wiv, biv, flag, UAt, VA, cv, dv);
    kA<<<NB, 256, 0, stream>>>(flag, y_t, t, Wt, bt, Win, bin_, Wq, bq, Wiq, biq,
        UAt, cv, u, cqv, w, l);
    kF<<<N / 128, 256, sizeof(KFS), stream>>>(flag, features, batch_idx, u, cqv, w, l);
    kE<<<NB, 256, 0, stream>>>(flag, w, l, VA, dv, Wo, bo, Wco, bco, Wout, bout, d_out);
}